// Round 2
// baseline (220951.123 us; speedup 1.0000x reference)
//
#include <hip/hip_runtime.h>
#include <hip/hip_cooperative_groups.h>
#include <math.h>
#include <cstddef>

namespace cg = cooperative_groups;

#define G3 3072

__device__ __forceinline__ float sigmoidf_(float x){ return 1.0f/(1.0f+expf(-x)); }

// ---------------------------------------------------------------------------
__global__ __launch_bounds__(256)
void zero_k(float* p, int n){
    int i = blockIdx.x*blockDim.x + threadIdx.x;
    for (int j = i; j < n; j += gridDim.x*blockDim.x) p[j] = 0.f;
}

// ---------------------------------------------------------------------------
// C[M x N] = A[M x K] @ B[K x N] (+bias). grid (N/64, M/16), block 256.
__global__ __launch_bounds__(256)
void gemm_k(const float* __restrict__ A, long lda,
            const float* __restrict__ Bm, long ldb,
            const float* __restrict__ bias,
            float* __restrict__ C, long ldc, int K)
{
    __shared__ float xs[16][64];
    const int tid = threadIdx.x;
    const int nl = tid & 31, bl = tid >> 5;
    const int n  = blockIdx.x*64 + nl*2;
    const int m0 = blockIdx.y*16;
    float a0x=0.f,a0y=0.f,a1x=0.f,a1y=0.f;
    for (int kc = 0; kc < K; kc += 64) {
        __syncthreads();
        { int r = tid >> 4, c = (tid & 15)*4;
          *(float4*)&xs[r][c] = *(const float4*)&A[(size_t)(m0+r)*lda + kc + c]; }
        __syncthreads();
        #pragma unroll 8
        for (int kk = 0; kk < 64; ++kk) {
            const float2 w = *(const float2*)&Bm[(size_t)(kc+kk)*ldb + n];
            const float xa = xs[bl][kk], xb = xs[bl+8][kk];
            a0x += xa*w.x; a0y += xa*w.y;
            a1x += xb*w.x; a1y += xb*w.y;
        }
    }
    float bx=0.f, by=0.f;
    if (bias){ bx = bias[n]; by = bias[n+1]; }
    float* c0 = &C[(size_t)(m0+bl)*ldc + n];
    float* c1 = &C[(size_t)(m0+bl+8)*ldc + n];
    c0[0]=a0x+bx; c0[1]=a0y+by; c1[0]=a1x+bx; c1[1]=a1y+by;
}

// ---------------------------------------------------------------------------
__global__ __launch_bounds__(512)
void bps_k(const float* __restrict__ bqm, const float* __restrict__ Wps,
           const float* __restrict__ bp, float* __restrict__ bps)
{
    const int n = threadIdx.x;
    float a = 0.f;
    #pragma unroll 8
    for (int k = 0; k < 128; ++k) a += bqm[k]*Wps[(size_t)k*512 + n];
    bps[n] = a + bp[n];
}

// ===========================================================================
// Persistent cooperative kernel: whole 3-level recurrence, grid.sync between
// phases. 1024 blocks x 256 threads, 4 blocks/CU (LDS 33.8KB, VGPR<=128).
// ===========================================================================
struct SeqArgs {
    const float* obs0; const float* obs1; const float* obs2;
    const float* Wp;  const float* bp;
    const float* Wih; const float* Whh; const float* bih; const float* bhh;
    const float* Wq;  const float* bq;
    const float* WqsA; const float* bpsA;
    float* out; float* dets1; float* dets2;
    float* HCu; float* qp; float* hp; float* giP; float* ghP;
};

__global__ __launch_bounds__(256, 4)
void seq_k(SeqArgs A)
{
    cg::grid_group grid = cg::this_grid();
    __shared__ float xs[64*132];                 // 33792 B, shared by all phases
    const int tid = threadIdx.x;
    const int bid = blockIdx.x;
    const int nb  = gridDim.x;

    const float* obsv[3] = {A.obs0, A.obs1, A.obs2};
    const int Tv[3] = {256, 64, 16};

    for (int level = 2; level >= 0; --level) {
        const int T = Tv[level];
        const float* o = obsv[level];
        float* dseq = (level==0) ? A.out : (level==1 ? A.dets1 : A.dets2);
        const float* ctxd = (level==2) ? nullptr : (level==1 ? A.dets2 : A.dets1);
        const int Tc = (level==1) ? 16 : 64;

        const float* Wp_l  = A.Wp + (size_t)level*1152*512;
        const float* Wpc   = Wp_l + (size_t)128*512;
        const float* bp_l  = A.bp + level*512;
        const float* Wih_l = A.Wih + (size_t)level*512*G3;
        const float* Whh_l = A.Whh + (size_t)level*1024*G3;
        const float* bih_l = A.bih + level*G3;
        const float* bhh_l = A.bhh + level*G3;
        const float* Wq_l  = A.Wq + (size_t)level*1536*512;
        const float* bq_l  = A.bq + level*512;
        const float* Wqs_l = A.WqsA + (size_t)level*512*512;
        const float* bps_l = A.bpsA + level*512;

        // ---- Phase HC: HCu[b*Tc+tc][512] = ctx @ Wpc (K=1024) ----
        if (level < 2) {
            const int NU = 128*Tc;               // 8 n-tiles x (M/8) m-tiles
            for (int vb = bid; vb < NU; vb += nb) {
                const int x = vb & 7, ym = vb >> 3;
                const int nl = tid & 31, mg = tid >> 5;
                const int n = x*64 + nl*2, m0 = ym*8;
                float ax=0.f, ay=0.f;
                for (int kc = 0; kc < 1024; kc += 128) {
                    __syncthreads();
                    { const int r = tid>>5, c = (tid&31)*4;
                      *(float4*)&xs[r*128+c] =
                          *(const float4*)&ctxd[(size_t)(m0+r)*1024 + kc + c]; }
                    __syncthreads();
                    const float* w = &Wpc[(size_t)kc*512 + n];
                    #pragma unroll 8
                    for (int kk = 0; kk < 128; ++kk) {
                        const float2 wv = *(const float2*)&w[(size_t)kk*512];
                        const float xv = xs[mg*128+kk];
                        ax += xv*wv.x; ay += xv*wv.y;
                    }
                }
                *(float2*)&A.HCu[(size_t)(m0+mg)*512 + n] = make_float2(ax,ay);
            }
            grid.sync();
        }

        for (int t = 0; t < T; ++t) {
            const float* dprev = dseq + (size_t)(t-1)*1024;   // valid for t>=1
            const long   ldd   = (long)T*1024;
            const float* op    = o + (size_t)(t-1)*512;
            const long   ldo   = (long)T*512;

            if (t > 0) {
                // ---- P1: qp[z][128][512]; z<8: det K-chunk, z>=8: obs K-chunk
                for (int vb = bid; vb < 1536; vb += nb) {
                    const int x = vb & 7, y = (vb>>3)&15, z = vb>>7;
                    const int nl = tid & 31, mg = tid >> 5;
                    const int n = x*64 + nl*2, m0 = y*8;
                    const float* src; long ld; int kr0;
                    if (z < 8) { src = dprev + z*128;   ld = ldd; kr0 = z*128; }
                    else       { src = op + (z-8)*128;  ld = ldo; kr0 = 1024 + (z-8)*128; }
                    __syncthreads();
                    { const int r = tid>>5, c = (tid&31)*4;
                      *(float4*)&xs[r*128+c] =
                          *(const float4*)&src[(size_t)(m0+r)*ld + c]; }
                    __syncthreads();
                    const float* w = &Wq_l[(size_t)kr0*512 + n];
                    float ax=0.f, ay=0.f;
                    #pragma unroll 8
                    for (int kk = 0; kk < 128; ++kk) {
                        const float2 wv = *(const float2*)&w[(size_t)kk*512];
                        const float xv = xs[mg*128+kk];
                        ax += xv*wv.x; ay += xv*wv.y;
                    }
                    *(float2*)&A.qp[(size_t)z*65536 + (size_t)(m0+mg)*512 + n]
                        = make_float2(ax,ay);
                }
                grid.sync();

                // ---- P2: hp[z][128][512] = qh @ Wqs chunk; qh = relu(sum qp + bq)
                for (int vb = bid; vb < 512; vb += nb) {
                    const int x = vb & 7, y = (vb>>3)&15, z = vb>>7;
                    const int nl = tid & 31, mg = tid >> 5;
                    const int n = x*64 + nl*2, m0 = y*8;
                    __syncthreads();
                    { const int r = tid>>5, c = (tid&31)*4;
                      const int kg = z*128 + c;
                      float4 s = *(const float4*)&bq_l[kg];
                      #pragma unroll
                      for (int cc = 0; cc < 12; ++cc) {
                          const float4 p = *(const float4*)&A.qp[(size_t)cc*65536
                                              + (size_t)(m0+r)*512 + kg];
                          s.x+=p.x; s.y+=p.y; s.z+=p.z; s.w+=p.w;
                      }
                      s.x=fmaxf(s.x,0.f); s.y=fmaxf(s.y,0.f);
                      s.z=fmaxf(s.z,0.f); s.w=fmaxf(s.w,0.f);
                      *(float4*)&xs[r*128+c] = s; }
                    __syncthreads();
                    const float* w = &Wqs_l[(size_t)(z*128)*512 + n];
                    float ax=0.f, ay=0.f;
                    #pragma unroll 8
                    for (int kk = 0; kk < 128; ++kk) {
                        const float2 wv = *(const float2*)&w[(size_t)kk*512];
                        const float xv = xs[mg*128+kk];
                        ax += xv*wv.x; ay += xv*wv.y;
                    }
                    *(float2*)&A.hp[(size_t)z*65536 + (size_t)(m0+mg)*512 + n]
                        = make_float2(ax,ay);
                }
                grid.sync();
            }

            // ---- P3: gru partials (gi: z<4 from h, gh: z>=4 from det_{t-1})
            const float* hbias = t ? bps_l : bp_l;
            const float* hcp = (level<2) ? A.HCu + (size_t)(t % Tc)*512 : nullptr;
            const long ldhc = (long)Tc*512;
            for (int vb = bid; vb < 1152; vb += nb) {
                const int x = vb % 48; const int rem = vb / 48;
                const int y = rem & 1, z = rem >> 1;
                if (t == 0 && z >= 4) continue;        // gh==0 at t=0 (block-uniform)
                const int nl = tid & 31, mg = tid >> 5;
                const int n = x*64 + nl*2, m0 = y*64;
                __syncthreads();
                if (z < 4) {
                    const int kb = z*128;
                    const int r = tid >> 2, c0 = (tid & 3)*32;
                    #pragma unroll
                    for (int i = 0; i < 8; ++i) {
                        const int c = c0 + i*4, kg = kb + c;
                        float4 s = *(const float4*)&hbias[kg];
                        if (hcp) {
                            const float4 p = *(const float4*)&hcp[(size_t)(m0+r)*ldhc + kg];
                            s.x+=p.x; s.y+=p.y; s.z+=p.z; s.w+=p.w;
                        }
                        if (t > 0) {
                            #pragma unroll
                            for (int cc = 0; cc < 4; ++cc) {
                                const float4 p = *(const float4*)&A.hp[(size_t)cc*65536
                                                    + (size_t)(m0+r)*512 + kg];
                                s.x+=p.x; s.y+=p.y; s.z+=p.z; s.w+=p.w;
                            }
                        }
                        s.x=fmaxf(s.x,0.f); s.y=fmaxf(s.y,0.f);
                        s.z=fmaxf(s.z,0.f); s.w=fmaxf(s.w,0.f);
                        *(float4*)&xs[r*132+c] = s;
                    }
                } else {
                    const int kb = (z-4)*128;
                    const int r = tid >> 2, c0 = (tid & 3)*32;
                    #pragma unroll
                    for (int i = 0; i < 8; ++i) {
                        const int c = c0 + i*4;
                        *(float4*)&xs[r*132+c] =
                            *(const float4*)&dprev[(size_t)(m0+r)*ldd + kb + c];
                    }
                }
                __syncthreads();
                const float* W; float* outp;
                if (z < 4) { W = Wih_l + (size_t)(z*128)*G3 + n;
                             outp = A.giP + (size_t)z*393216; }
                else       { W = Whh_l + (size_t)((z-4)*128)*G3 + n;
                             outp = A.ghP + (size_t)(z-4)*393216; }
                float2 acc[8];
                #pragma unroll
                for (int j = 0; j < 8; ++j) acc[j] = make_float2(0.f,0.f);
                const int rb = mg*8;
                #pragma unroll 4
                for (int kk = 0; kk < 128; ++kk) {
                    const float2 wv = *(const float2*)&W[(size_t)kk*G3];
                    #pragma unroll
                    for (int j = 0; j < 8; ++j) {
                        const float xv = xs[(rb+j)*132+kk];
                        acc[j].x += xv*wv.x; acc[j].y += xv*wv.y;
                    }
                }
                #pragma unroll
                for (int j = 0; j < 8; ++j)
                    *(float2*)&outp[(size_t)(m0+rb+j)*G3 + n] = acc[j];
            }
            grid.sync();

            // ---- P4: epilogue (GRU pointwise), writes det_t ----
            for (int vb = bid; vb < 512; vb += nb) {
                const int x = vb & 3, b = vb >> 2;
                const int d = x*256 + tid;
                float gir=0.f,giz=0.f,gin=0.f;
                #pragma unroll
                for (int c = 0; c < 4; ++c) {
                    const float* p = &A.giP[(size_t)c*393216 + (size_t)b*G3 + d];
                    gir += p[0]; giz += p[1024]; gin += p[2048];
                }
                float ghr=0.f,ghz=0.f,ghn=0.f;
                if (t > 0) {
                    #pragma unroll
                    for (int c = 0; c < 8; ++c) {
                        const float* p = &A.ghP[(size_t)c*393216 + (size_t)b*G3 + d];
                        ghr += p[0]; ghz += p[1024]; ghn += p[2048];
                    }
                }
                const float r  = sigmoidf_(gir + ghr + bih_l[d] + bhh_l[d]);
                const float zz = sigmoidf_(giz + ghz + bih_l[1024+d] + bhh_l[1024+d]);
                const float nn = tanhf(gin + bih_l[2048+d] + r*(ghn + bhh_l[2048+d]));
                const float dold = t ? dprev[(size_t)b*ldd + d] : 0.f;
                dseq[((size_t)b*T + t)*1024 + d] = (1.f - zz)*nn + zz*dold;
            }
            grid.sync();
        }
    }
}

// ===========================================================================
// Fallback path kernels (round-1 verified) — used only if cooperative launch
// is rejected by the runtime.
// ===========================================================================
__global__ __launch_bounds__(256)
void qh_part_k(const float* __restrict__ det, long ld_det,
               const float* __restrict__ obs, long ld_obs,
               const float* __restrict__ Wq,
               float* __restrict__ qp)
{
    __shared__ float xs[8][256];
    const int tid = threadIdx.x;
    const int nl = tid & 31, mg = tid >> 5;
    const int n  = blockIdx.x*64 + nl*2;
    const int m0 = blockIdx.y*8;
    const int cz = blockIdx.z;
    const float* As; long lda; int kr0;
    if (cz < 4) { As = det + cz*256;     lda = ld_det; kr0 = cz*256; }
    else        { As = obs + (cz-4)*256; lda = ld_obs; kr0 = 1024 + (cz-4)*256; }
    {
        const int r = tid >> 5, c = (tid & 31)*8;
        const float* src = &As[(size_t)(m0+r)*lda + c];
        *(float4*)&xs[r][c]   = *(const float4*)&src[0];
        *(float4*)&xs[r][c+4] = *(const float4*)&src[4];
    }
    __syncthreads();
    const float* w = &Wq[(size_t)kr0*512 + n];
    float ax=0.f, ay=0.f;
    #pragma unroll 8
    for (int kk = 0; kk < 256; ++kk) {
        const float2 wv = *(const float2*)&w[(size_t)kk*512];
        const float x = xs[mg][kk];
        ax += x*wv.x; ay += x*wv.y;
    }
    *(float2*)&qp[(size_t)cz*65536 + (size_t)(m0+mg)*512 + n] = make_float2(ax, ay);
}

__global__ __launch_bounds__(256)
void h_part_k(const float* __restrict__ qp, const float* __restrict__ bq,
              const float* __restrict__ Wqs, float* __restrict__ hp)
{
    __shared__ float xs[8][128];
    const int tid = threadIdx.x;
    const int nl = tid & 31, mg = tid >> 5;
    const int n  = blockIdx.x*64 + nl*2;
    const int m0 = blockIdx.y*8;
    const int kz = blockIdx.z;
    {
        const int r = tid >> 5, c = (tid & 31)*4;
        const int kg = kz*128 + c;
        float4 s = *(const float4*)&bq[kg];
        #pragma unroll
        for (int cc = 0; cc < 6; ++cc) {
            const float4 p = *(const float4*)&qp[(size_t)cc*65536 + (size_t)(m0+r)*512 + kg];
            s.x += p.x; s.y += p.y; s.z += p.z; s.w += p.w;
        }
        s.x = fmaxf(s.x,0.f); s.y = fmaxf(s.y,0.f);
        s.z = fmaxf(s.z,0.f); s.w = fmaxf(s.w,0.f);
        *(float4*)&xs[r][c] = s;
    }
    __syncthreads();
    const float* w = &Wqs[(size_t)(kz*128)*512 + n];
    float ax=0.f, ay=0.f;
    #pragma unroll 8
    for (int kk = 0; kk < 128; ++kk) {
        const float2 wv = *(const float2*)&w[(size_t)kk*512];
        const float x = xs[mg][kk];
        ax += x*wv.x; ay += x*wv.y;
    }
    *(float2*)&hp[(size_t)kz*65536 + (size_t)(m0+mg)*512 + n] = make_float2(ax, ay);
}

__global__ __launch_bounds__(256)
void gru_part_k(const float* __restrict__ hp,
                const float* __restrict__ hc, long ld_hc,
                const float* __restrict__ hbias,
                const float* __restrict__ det, long ld_det,
                const float* __restrict__ Wih, const float* __restrict__ Whh,
                float* __restrict__ giP, float* __restrict__ ghP)
{
    __shared__ float xs[64][132];
    const int tid = threadIdx.x;
    const int nl = tid & 31, mg = tid >> 5;
    const int n  = blockIdx.x*64 + nl*2;
    const int m0 = blockIdx.y*64;
    const int zc = blockIdx.z;
    const bool is_gi = (zc < 4);
    {
        const int r = tid >> 2, c0 = (tid & 3)*32;
        if (is_gi) {
            const int kb = zc*128;
            #pragma unroll
            for (int i = 0; i < 8; ++i) {
                const int c = c0 + i*4, kg = kb + c;
                float4 s = *(const float4*)&hbias[kg];
                if (hc) {
                    const float4 p = *(const float4*)&hc[(size_t)(m0+r)*ld_hc + kg];
                    s.x+=p.x; s.y+=p.y; s.z+=p.z; s.w+=p.w;
                }
                if (hp) {
                    #pragma unroll
                    for (int cc = 0; cc < 4; ++cc) {
                        const float4 p = *(const float4*)&hp[(size_t)cc*65536 + (size_t)(m0+r)*512 + kg];
                        s.x+=p.x; s.y+=p.y; s.z+=p.z; s.w+=p.w;
                    }
                }
                s.x=fmaxf(s.x,0.f); s.y=fmaxf(s.y,0.f);
                s.z=fmaxf(s.z,0.f); s.w=fmaxf(s.w,0.f);
                *(float4*)&xs[r][c] = s;
            }
        } else {
            const int kb = (zc-4)*128;
            #pragma unroll
            for (int i = 0; i < 8; ++i) {
                const int c = c0 + i*4;
                *(float4*)&xs[r][c] = *(const float4*)&det[(size_t)(m0+r)*ld_det + kb + c];
            }
        }
    }
    __syncthreads();
    const float* W; float* out;
    if (is_gi) { W = Wih + (size_t)(zc*128)*G3 + n;     out = giP + (size_t)zc*393216; }
    else       { W = Whh + (size_t)((zc-4)*128)*G3 + n; out = ghP + (size_t)(zc-4)*393216; }
    float2 acc[8];
    #pragma unroll
    for (int j = 0; j < 8; ++j) acc[j] = make_float2(0.f, 0.f);
    const int rb = mg*8;
    #pragma unroll 4
    for (int kk = 0; kk < 128; ++kk) {
        const float2 wv = *(const float2*)&W[(size_t)kk*G3];
        #pragma unroll
        for (int j = 0; j < 8; ++j) {
            const float x = xs[rb+j][kk];
            acc[j].x += x*wv.x; acc[j].y += x*wv.y;
        }
    }
    #pragma unroll
    for (int j = 0; j < 8; ++j)
        *(float2*)&out[(size_t)(m0+rb+j)*G3 + n] = acc[j];
}

__global__ __launch_bounds__(256)
void gru_epi_k(const float* __restrict__ giP, const float* __restrict__ ghP,
               const float* __restrict__ bih, const float* __restrict__ bhh,
               const float* __restrict__ det_in, long ld_det,
               float* __restrict__ det_out, long ld_out)
{
    const int d = blockIdx.x*256 + threadIdx.x;
    const int b = blockIdx.y;
    float gir=0.f, giz=0.f, gin=0.f;
    #pragma unroll
    for (int c = 0; c < 4; ++c) {
        const float* p = &giP[(size_t)c*393216 + (size_t)b*G3 + d];
        gir += p[0]; giz += p[1024]; gin += p[2048];
    }
    float ghr=0.f, ghz=0.f, ghn=0.f;
    #pragma unroll
    for (int c = 0; c < 8; ++c) {
        const float* p = &ghP[(size_t)c*393216 + (size_t)b*G3 + d];
        ghr += p[0]; ghz += p[1024]; ghn += p[2048];
    }
    const float r  = sigmoidf_(gir + ghr + bih[d] + bhh[d]);
    const float z  = sigmoidf_(giz + ghz + bih[1024+d] + bhh[1024+d]);
    const float nn = tanhf(gin + bih[2048+d] + r*(ghn + bhh[2048+d]));
    const float dold = det_in[(size_t)b*ld_det + d];
    det_out[(size_t)b*ld_out + d] = (1.f - z)*nn + z*dold;
}

// ---------------------------------------------------------------------------
extern "C" void kernel_launch(void* const* d_in, const int* in_sizes, int n_in,
                              void* d_out, int out_size, void* d_ws, size_t ws_size,
                              hipStream_t stream)
{
    const float* obs0 = (const float*)d_in[0];
    const float* obs1 = (const float*)d_in[1];
    const float* obs2 = (const float*)d_in[2];
    const float* Wp   = (const float*)d_in[3];
    const float* bp   = (const float*)d_in[4];
    const float* Wih  = (const float*)d_in[5];
    const float* Whh  = (const float*)d_in[6];
    const float* bih  = (const float*)d_in[7];
    const float* bhh  = (const float*)d_in[8];
    const float* Wq   = (const float*)d_in[9];
    const float* bq   = (const float*)d_in[10];
    const float* Wqm  = (const float*)d_in[11];
    const float* bqm  = (const float*)d_in[12];

    float* ws = (float*)d_ws;
    float* det0 = ws;  ws += (size_t)128*1024;      // fallback only
    float* WqsA = ws;  ws += (size_t)3*512*512;
    float* bpsA = ws;  ws += (size_t)3*512;
    float* dets2= ws;  ws += (size_t)128*16*1024;
    float* dets1= ws;  ws += (size_t)128*64*1024;
    float* HCu  = ws;  ws += (size_t)128*64*512;
    float* qp   = ws;  ws += (size_t)12*128*512;    // 12 chunks (coop), >=6 (fallback)
    float* hp   = ws;  ws += (size_t)4*128*512;
    float* giP  = ws;  ws += (size_t)4*128*3072;
    float* ghP  = ws;  ws += (size_t)8*128*3072;

    // Per-level precompute: Wqs = Wqm @ Wp_s ; bps = bp + bqm @ Wp_s
    for (int l = 0; l < 3; ++l) {
        const float* Wp_l = Wp + (size_t)l*1152*512;
        gemm_k<<<dim3(8,32), dim3(256), 0, stream>>>(
            Wqm + (size_t)l*512*128, 128, Wp_l, 512, nullptr,
            WqsA + (size_t)l*512*512, 512, 128);
        bps_k<<<dim3(1), dim3(512), 0, stream>>>(
            bqm + (size_t)l*128, Wp_l, bp + (size_t)l*512, bpsA + (size_t)l*512);
    }

    SeqArgs ha;
    ha.obs0 = obs0; ha.obs1 = obs1; ha.obs2 = obs2;
    ha.Wp = Wp; ha.bp = bp; ha.Wih = Wih; ha.Whh = Whh;
    ha.bih = bih; ha.bhh = bhh; ha.Wq = Wq; ha.bq = bq;
    ha.WqsA = WqsA; ha.bpsA = bpsA;
    ha.out = (float*)d_out; ha.dets1 = dets1; ha.dets2 = dets2;
    ha.HCu = HCu; ha.qp = qp; ha.hp = hp; ha.giP = giP; ha.ghP = ghP;
    void* kp[] = { &ha };
    hipError_t rc = hipLaunchCooperativeKernel((const void*)seq_k,
                        dim3(1024), dim3(256), kp, 0, stream);

    if (rc != hipSuccess) {
        // ---------------- fallback: round-1 verified launch sequence --------
        zero_k<<<dim3(128), dim3(256), 0, stream>>>(det0, 128*1024);
        const float* obsv[3] = {obs0, obs1, obs2};
        const int Tv[3] = {256, 64, 16};
        for (int level = 2; level >= 0; --level) {
            const int T = Tv[level];
            const float* o = obsv[level];
            float* dseq = (level == 0) ? (float*)d_out : (level == 1 ? dets1 : dets2);
            const float* ctxd = (level == 2) ? nullptr : (level == 1 ? dets2 : dets1);
            const int Tc = (level == 1) ? 16 : 64;

            const float* Wp_l  = Wp  + (size_t)level*1152*512;
            const float* Wpc_l = Wp_l + (size_t)128*512;
            const float* bp_l  = bp  + (size_t)level*512;
            const float* Wih_l = Wih + (size_t)level*512*3072;
            const float* Whh_l = Whh + (size_t)level*1024*3072;
            const float* bih_l = bih + (size_t)level*3072;
            const float* bhh_l = bhh + (size_t)level*3072;
            const float* Wq_l  = Wq  + (size_t)level*1536*512;
            const float* bq_l  = bq  + (size_t)level*512;
            const float* Wqs_l = WqsA + (size_t)level*512*512;
            const float* bps_l = bpsA + (size_t)level*512;

            if (level < 2) {
                gemm_k<<<dim3(8, (128*Tc)/16), dim3(256), 0, stream>>>(
                    ctxd, 1024, Wpc_l, 512, nullptr, HCu, 512, 1024);
            }
            for (int t = 0; t < T; ++t) {
                if (t > 0) {
                    qh_part_k<<<dim3(8,16,6), dim3(256), 0, stream>>>(
                        dseq + (size_t)(t-1)*1024, (long)T*1024,
                        o + (size_t)(t-1)*512,  (long)T*512, Wq_l, qp);
                    h_part_k<<<dim3(8,16,4), dim3(256), 0, stream>>>(qp, bq_l, Wqs_l, hp);
                }
                const float* hc_t  = (level < 2) ? HCu + (size_t)(t % Tc)*512 : nullptr;
                const float* dprev = t ? dseq + (size_t)(t-1)*1024 : det0;
                const long   ldprev = t ? (long)T*1024 : 1024L;
                gru_part_k<<<dim3(48,2,12), dim3(256), 0, stream>>>(
                    t ? hp : nullptr, hc_t, (long)Tc*512,
                    t ? bps_l : bp_l, dprev, ldprev,
                    Wih_l, Whh_l, giP, ghP);
                gru_epi_k<<<dim3(4,128), dim3(256), 0, stream>>>(
                    giP, ghP, bih_l, bhh_l, dprev, ldprev,
                    dseq + (size_t)t*1024, (long)T*1024);
            }
        }
    }
}

// Round 3
// 23471.480 us; speedup vs baseline: 9.4136x; 9.4136x over previous
//
#include <hip/hip_runtime.h>
#include <math.h>
#include <cstddef>

#define G3 3072

__device__ __forceinline__ float sigmoidf_(float x){ return 1.0f/(1.0f+expf(-x)); }

// ---------------------------------------------------------------------------
__global__ __launch_bounds__(256)
void zero_k(float* p, int n){
    int i = blockIdx.x*blockDim.x + threadIdx.x;
    for (int j = i; j < n; j += gridDim.x*blockDim.x) p[j] = 0.f;
}

// ---------------------------------------------------------------------------
// C[M x N] = A[M x K] @ B[K x N] (+bias). grid (N/64, M/16), block 256.
// Used for per-level Wqs fold and the per-level HC = ctx @ Wpc precompute.
__global__ __launch_bounds__(256)
void gemm_k(const float* __restrict__ A, long lda,
            const float* __restrict__ Bm, long ldb,
            const float* __restrict__ bias,
            float* __restrict__ C, long ldc, int K)
{
    __shared__ float xs[16][64];
    const int tid = threadIdx.x;
    const int nl = tid & 31, bl = tid >> 5;
    const int n  = blockIdx.x*64 + nl*2;
    const int m0 = blockIdx.y*16;
    float a0x=0.f,a0y=0.f,a1x=0.f,a1y=0.f;
    for (int kc = 0; kc < K; kc += 64) {
        __syncthreads();
        { int r = tid >> 4, c = (tid & 15)*4;
          *(float4*)&xs[r][c] = *(const float4*)&A[(size_t)(m0+r)*lda + kc + c]; }
        __syncthreads();
        #pragma unroll 8
        for (int kk = 0; kk < 64; ++kk) {
            const float2 w = *(const float2*)&Bm[(size_t)(kc+kk)*ldb + n];
            const float xa = xs[bl][kk], xb = xs[bl+8][kk];
            a0x += xa*w.x; a0y += xa*w.y;
            a1x += xb*w.x; a1y += xb*w.y;
        }
    }
    float bx=0.f, by=0.f;
    if (bias){ bx = bias[n]; by = bias[n+1]; }
    float* c0 = &C[(size_t)(m0+bl)*ldc + n];
    float* c1 = &C[(size_t)(m0+bl+8)*ldc + n];
    c0[0]=a0x+bx; c0[1]=a0y+by; c1[0]=a1x+bx; c1[1]=a1y+by;
}

// ---------------------------------------------------------------------------
// bps = bp + bqm @ Wp_s   (Wp_s = first 128 rows of Wp_l). 1 block x 512.
__global__ __launch_bounds__(512)
void bps_k(const float* __restrict__ bqm, const float* __restrict__ Wps,
           const float* __restrict__ bp, float* __restrict__ bps)
{
    const int n = threadIdx.x;
    float a = 0.f;
    #pragma unroll 8
    for (int k = 0; k < 128; ++k) a += bqm[k]*Wps[(size_t)k*512 + n];
    bps[n] = a + bp[n];
}

// ---------------------------------------------------------------------------
// qp[cz][128][512] partial of (det @ Wq[0:1024] + obs @ Wq[1024:1536]).
// cz 0..3 -> det K-chunk cz*256 ; cz 4..5 -> obs K-chunk (cz-4)*256.
// grid (8, 16, 6), block 256.
__global__ __launch_bounds__(256)
void qh_part_k(const float* __restrict__ det, long ld_det,   // pre-offset, step t-1
               const float* __restrict__ obs, long ld_obs,   // pre-offset, step t-1
               const float* __restrict__ Wq,                  // 1536 x 512
               float* __restrict__ qp)                        // 6 x 128 x 512
{
    __shared__ float xs[8][256];
    const int tid = threadIdx.x;
    const int nl = tid & 31, mg = tid >> 5;
    const int n  = blockIdx.x*64 + nl*2;
    const int m0 = blockIdx.y*8;
    const int cz = blockIdx.z;
    const float* As; long lda; int kr0;
    if (cz < 4) { As = det + cz*256;     lda = ld_det; kr0 = cz*256; }
    else        { As = obs + (cz-4)*256; lda = ld_obs; kr0 = 1024 + (cz-4)*256; }
    {   // stage A-tile 8 rows x 256 cols
        const int r = tid >> 5, c = (tid & 31)*8;
        const float* src = &As[(size_t)(m0+r)*lda + c];
        *(float4*)&xs[r][c]   = *(const float4*)&src[0];
        *(float4*)&xs[r][c+4] = *(const float4*)&src[4];
    }
    __syncthreads();
    const float* w = &Wq[(size_t)kr0*512 + n];
    float ax=0.f, ay=0.f;
    #pragma unroll 8
    for (int kk = 0; kk < 256; ++kk) {
        const float2 wv = *(const float2*)&w[(size_t)kk*512];
        const float x = xs[mg][kk];
        ax += x*wv.x; ay += x*wv.y;
    }
    *(float2*)&qp[(size_t)cz*65536 + (size_t)(m0+mg)*512 + n] = make_float2(ax, ay);
}

// ---------------------------------------------------------------------------
// hp[kz][128][512] partial of qh @ Wqs, where qh = relu(sum_c qp[c] + bq)
// is materialized during the A-stage. grid (8, 16, 4), block 256.
__global__ __launch_bounds__(256)
void h_part_k(const float* __restrict__ qp, const float* __restrict__ bq,
              const float* __restrict__ Wqs, float* __restrict__ hp)
{
    __shared__ float xs[8][128];
    const int tid = threadIdx.x;
    const int nl = tid & 31, mg = tid >> 5;
    const int n  = blockIdx.x*64 + nl*2;
    const int m0 = blockIdx.y*8;
    const int kz = blockIdx.z;
    {   // stage: qh[m0..m0+7][kz*128 .. +127] = relu(sum qp + bq)
        const int r = tid >> 5, c = (tid & 31)*4;
        const int kg = kz*128 + c;
        float4 s = *(const float4*)&bq[kg];
        #pragma unroll
        for (int cc = 0; cc < 6; ++cc) {
            const float4 p = *(const float4*)&qp[(size_t)cc*65536 + (size_t)(m0+r)*512 + kg];
            s.x += p.x; s.y += p.y; s.z += p.z; s.w += p.w;
        }
        s.x = fmaxf(s.x,0.f); s.y = fmaxf(s.y,0.f);
        s.z = fmaxf(s.z,0.f); s.w = fmaxf(s.w,0.f);
        *(float4*)&xs[r][c] = s;
    }
    __syncthreads();
    const float* w = &Wqs[(size_t)(kz*128)*512 + n];
    float ax=0.f, ay=0.f;
    #pragma unroll 8
    for (int kk = 0; kk < 128; ++kk) {
        const float2 wv = *(const float2*)&w[(size_t)kk*512];
        const float x = xs[mg][kk];
        ax += x*wv.x; ay += x*wv.y;
    }
    *(float2*)&hp[(size_t)kz*65536 + (size_t)(m0+mg)*512 + n] = make_float2(ax, ay);
}

// ---------------------------------------------------------------------------
// GRU partial GEMMs, vectorized inner loop.
//   z<4 : giP[z] += (h-tile) @ Wih K-chunk z*128, h built in A-stage
//   z>=4: ghP[z-4] = det @ Whh K-chunk (z-4)*128
// grid (24, 4, 12), block 256. Thread: 4 rows x 4 cols; kk unrolled x4 so
// LDS activations load as ds_read_b128 (broadcast across lanes) and weights
// as global_load_dwordx4. 64 FMA per 4 LDS instrs -> VALU-issue-bound.
__global__ __launch_bounds__(256)
void gru_part_k(const float* __restrict__ hp,       // 4x128x512, or null (t==0)
                const float* __restrict__ hc, long ld_hc,  // pre-offset; or null
                const float* __restrict__ hbias,    // bps (t>0) or bp (t==0)
                const float* __restrict__ det, long ld_det,
                const float* __restrict__ Wih, const float* __restrict__ Whh,
                float* __restrict__ giP, float* __restrict__ ghP)
{
    __shared__ float xs[32*132];                     // 16.9 KB
    const int tid = threadIdx.x;
    const int nl = tid & 31, mg = tid >> 5;
    const int n  = blockIdx.x*128 + nl*4;            // 24 x-blocks cover 3072
    const int m0 = blockIdx.y*32;                    // 4 y-blocks cover 128 rows
    const int zc = blockIdx.z;
    const bool is_gi = (zc < 4);
    {   // stage A-tile 32 rows x 128 cols: r = tid>>3 (32 rows), 8 thr x 16 cols
        const int r = tid >> 3, c0 = (tid & 7)*16;
        if (is_gi) {
            const int kb = zc*128;
            #pragma unroll
            for (int i = 0; i < 4; ++i) {
                const int c = c0 + i*4, kg = kb + c;
                float4 s = *(const float4*)&hbias[kg];
                if (hc) {
                    const float4 p = *(const float4*)&hc[(size_t)(m0+r)*ld_hc + kg];
                    s.x+=p.x; s.y+=p.y; s.z+=p.z; s.w+=p.w;
                }
                if (hp) {
                    #pragma unroll
                    for (int cc = 0; cc < 4; ++cc) {
                        const float4 p = *(const float4*)&hp[(size_t)cc*65536 + (size_t)(m0+r)*512 + kg];
                        s.x+=p.x; s.y+=p.y; s.z+=p.z; s.w+=p.w;
                    }
                }
                s.x=fmaxf(s.x,0.f); s.y=fmaxf(s.y,0.f);
                s.z=fmaxf(s.z,0.f); s.w=fmaxf(s.w,0.f);
                *(float4*)&xs[r*132 + c] = s;
            }
        } else {
            const int kb = (zc-4)*128;
            #pragma unroll
            for (int i = 0; i < 4; ++i) {
                const int c = c0 + i*4;
                *(float4*)&xs[r*132 + c] =
                    *(const float4*)&det[(size_t)(m0+r)*ld_det + kb + c];
            }
        }
    }
    __syncthreads();
    const float* W; float* outp;
    if (is_gi) { W = Wih + (size_t)(zc*128)*G3 + n;     outp = giP + (size_t)zc*393216; }
    else       { W = Whh + (size_t)((zc-4)*128)*G3 + n; outp = ghP + (size_t)(zc-4)*393216; }
    float4 acc[4];
    #pragma unroll
    for (int j = 0; j < 4; ++j) acc[j] = make_float4(0.f,0.f,0.f,0.f);
    const int rb = mg*4;                             // 4 rows per thread
    #pragma unroll 2
    for (int kc4 = 0; kc4 < 128; kc4 += 4) {
        float4 xv[4];
        #pragma unroll
        for (int j = 0; j < 4; ++j)
            xv[j] = *(const float4*)&xs[(rb+j)*132 + kc4];   // b128, lane-broadcast
        #pragma unroll
        for (int kk = 0; kk < 4; ++kk) {
            const float4 wv = *(const float4*)&W[(size_t)(kc4+kk)*G3];
            #pragma unroll
            for (int j = 0; j < 4; ++j) {
                const float xj = (kk==0) ? xv[j].x : (kk==1) ? xv[j].y
                               : (kk==2) ? xv[j].z : xv[j].w;
                acc[j].x += xj*wv.x; acc[j].y += xj*wv.y;
                acc[j].z += xj*wv.z; acc[j].w += xj*wv.w;
            }
        }
    }
    #pragma unroll
    for (int j = 0; j < 4; ++j)
        *(float4*)&outp[(size_t)(m0+rb+j)*G3 + n] = acc[j];
}

// ---------------------------------------------------------------------------
// GRU pointwise from partials. grid (4, 128), block 256.
__global__ __launch_bounds__(256)
void gru_epi_k(const float* __restrict__ giP, const float* __restrict__ ghP,
               const float* __restrict__ bih, const float* __restrict__ bhh,
               const float* __restrict__ det_in, long ld_det,
               float* __restrict__ det_out, long ld_out)
{
    const int d = blockIdx.x*256 + threadIdx.x;
    const int b = blockIdx.y;
    float gir=0.f, giz=0.f, gin=0.f;
    #pragma unroll
    for (int c = 0; c < 4; ++c) {
        const float* p = &giP[(size_t)c*393216 + (size_t)b*G3 + d];
        gir += p[0]; giz += p[1024]; gin += p[2048];
    }
    float ghr=0.f, ghz=0.f, ghn=0.f;
    #pragma unroll
    for (int c = 0; c < 8; ++c) {
        const float* p = &ghP[(size_t)c*393216 + (size_t)b*G3 + d];
        ghr += p[0]; ghz += p[1024]; ghn += p[2048];
    }
    const float r  = sigmoidf_(gir + ghr + bih[d] + bhh[d]);
    const float z  = sigmoidf_(giz + ghz + bih[1024+d] + bhh[1024+d]);
    const float nn = tanhf(gin + bih[2048+d] + r*(ghn + bhh[2048+d]));
    const float dold = det_in[(size_t)b*ld_det + d];
    det_out[(size_t)b*ld_out + d] = (1.f - z)*nn + z*dold;
}

// ---------------------------------------------------------------------------
extern "C" void kernel_launch(void* const* d_in, const int* in_sizes, int n_in,
                              void* d_out, int out_size, void* d_ws, size_t ws_size,
                              hipStream_t stream)
{
    const float* obs0 = (const float*)d_in[0];
    const float* obs1 = (const float*)d_in[1];
    const float* obs2 = (const float*)d_in[2];
    const float* Wp   = (const float*)d_in[3];
    const float* bp   = (const float*)d_in[4];
    const float* Wih  = (const float*)d_in[5];
    const float* Whh  = (const float*)d_in[6];
    const float* bih  = (const float*)d_in[7];
    const float* bhh  = (const float*)d_in[8];
    const float* Wq   = (const float*)d_in[9];
    const float* bq   = (const float*)d_in[10];
    const float* Wqm  = (const float*)d_in[11];
    const float* bqm  = (const float*)d_in[12];

    float* ws = (float*)d_ws;
    float* det0 = ws;  ws += (size_t)128*1024;      // zero initial state
    float* WqsA = ws;  ws += (size_t)3*512*512;     // folded Wqm@Wp_s per level
    float* bpsA = ws;  ws += (size_t)3*512;         // folded bias per level
    float* dets2= ws;  ws += (size_t)128*16*1024;
    float* dets1= ws;  ws += (size_t)128*64*1024;
    float* HCu  = ws;  ws += (size_t)128*64*512;    // ctx@Wpc per level (reused)
    float* qp   = ws;  ws += (size_t)6*128*512;     // qh partials (6 K-chunks)
    float* hp   = ws;  ws += (size_t)4*128*512;     // h partials (4 K-chunks)
    float* giP  = ws;  ws += (size_t)4*128*3072;    // gi partials
    float* ghP  = ws;  ws += (size_t)8*128*3072;    // gh partials

    zero_k<<<dim3(128), dim3(256), 0, stream>>>(det0, 128*1024);

    // Per-level precompute: Wqs = Wqm @ Wp_s ; bps = bp + bqm @ Wp_s
    for (int l = 0; l < 3; ++l) {
        const float* Wp_l = Wp + (size_t)l*1152*512;
        gemm_k<<<dim3(8,32), dim3(256), 0, stream>>>(
            Wqm + (size_t)l*512*128, 128, Wp_l, 512, nullptr,
            WqsA + (size_t)l*512*512, 512, 128);
        bps_k<<<dim3(1), dim3(512), 0, stream>>>(
            bqm + (size_t)l*128, Wp_l, bp + (size_t)l*512, bpsA + (size_t)l*512);
    }

    const float* obsv[3] = {obs0, obs1, obs2};
    const int Tv[3] = {256, 64, 16};

    for (int level = 2; level >= 0; --level) {
        const int T = Tv[level];
        const float* o = obsv[level];
        float* dseq = (level == 0) ? (float*)d_out : (level == 1 ? dets1 : dets2);
        const float* ctxd = (level == 2) ? nullptr : (level == 1 ? dets2 : dets1);
        const int Tc = (level == 1) ? 16 : 64;

        const float* Wp_l  = Wp  + (size_t)level*1152*512;
        const float* Wpc_l = Wp_l + (size_t)128*512;     // ctx rows of Wp
        const float* bp_l  = bp  + (size_t)level*512;
        const float* Wih_l = Wih + (size_t)level*512*3072;
        const float* Whh_l = Whh + (size_t)level*1024*3072;
        const float* bih_l = bih + (size_t)level*3072;
        const float* bhh_l = bhh + (size_t)level*3072;
        const float* Wq_l  = Wq  + (size_t)level*1536*512;
        const float* bq_l  = bq  + (size_t)level*512;
        const float* Wqs_l = WqsA + (size_t)level*512*512;
        const float* bps_l = bpsA + (size_t)level*512;

        // Hoisted: HCu[(b*Tc+tc)][512] = ctx @ Wpc (previous level's output is final)
        if (level < 2) {
            gemm_k<<<dim3(8, (128*Tc)/16), dim3(256), 0, stream>>>(
                ctxd, 1024, Wpc_l, 512, nullptr, HCu, 512, 1024);
        }

        for (int t = 0; t < T; ++t) {
            if (t > 0) {
                qh_part_k<<<dim3(8,16,6), dim3(256), 0, stream>>>(
                    dseq + (size_t)(t-1)*1024, (long)T*1024,
                    o + (size_t)(t-1)*512,  (long)T*512, Wq_l, qp);
                h_part_k<<<dim3(8,16,4), dim3(256), 0, stream>>>(qp, bq_l, Wqs_l, hp);
            }
            const float* hc_t  = (level < 2) ? HCu + (size_t)(t % Tc)*512 : nullptr;
            const float* dprev = t ? dseq + (size_t)(t-1)*1024 : det0;
            const long   ldprev = t ? (long)T*1024 : 1024L;
            gru_part_k<<<dim3(24,4,12), dim3(256), 0, stream>>>(
                t ? hp : nullptr, hc_t, (long)Tc*512,
                t ? bps_l : bp_l, dprev, ldprev,
                Wih_l, Whh_l, giP, ghP);
            gru_epi_k<<<dim3(4,128), dim3(256), 0, stream>>>(
                giP, ghP, bih_l, bhh_l, dprev, ldprev,
                dseq + (size_t)t*1024, (long)T*1024);
        }
    }
}